// Round 4
// baseline (263.020 us; speedup 1.0000x reference)
//
#include <hip/hip_runtime.h>
#include <cstddef>

// ---------------------------------------------------------------------------
// B=2, N=2048, C=1024, H=16, Dh=64, scale = Dh//H = 4
// qkv: [4096x1024] x [3072x1024]^T  -> q|k|v fp32 [B,H,N,64]   (bf16x3 split MFMA)
// attn: banded softmax (masked logits = 1e-9 folded analytically), fp32,
//       LDS-free / barrier-free, 8 lanes per query row.
// proj: [4096x1024] x [1024x1024]^T + bias -> out fp32          (bf16 MFMA)
// ---------------------------------------------------------------------------

typedef short  bf16x8 __attribute__((ext_vector_type(8)));
typedef float  f32x4  __attribute__((ext_vector_type(4)));

__device__ __forceinline__ void gl_lds16(const void* g, void* l) {
    __builtin_amdgcn_global_load_lds(
        (const __attribute__((address_space(1))) void*)g,
        (__attribute__((address_space(3))) void*)l, 16, 0, 0);
}

__device__ __forceinline__ ushort f2bf_rne(float f) {
    unsigned b = __float_as_uint(f);
    b += 0x7FFFu + ((b >> 16) & 1u);
    return (ushort)(b >> 16);
}

// ---------------------------------------------------------------------------
// fused fp32 -> bf16 split for all three tensors in one launch.
// ---------------------------------------------------------------------------
__global__ void split_all(const float* __restrict__ x,
                          const float* __restrict__ qkvw,
                          const float* __restrict__ projw,
                          ushort* __restrict__ xh, ushort* __restrict__ xl,
                          ushort* __restrict__ wh, ushort* __restrict__ wl,
                          ushort* __restrict__ pwh)
{
    const int i = blockIdx.x * 256 + threadIdx.x;
    const float* src; ushort* hi; ushort* lo; int j;
    if (i < 1048576)      { src = x;     hi = xh;  lo = xl;     j = i; }
    else if (i < 1835008) { src = qkvw;  hi = wh;  lo = wl;     j = i - 1048576; }
    else                  { src = projw; hi = pwh; lo = nullptr; j = i - 1835008; }

    float4 v = ((const float4*)src)[j];
    ushort h0 = f2bf_rne(v.x), h1 = f2bf_rne(v.y), h2 = f2bf_rne(v.z), h3 = f2bf_rne(v.w);
    ((ushort4*)hi)[j] = make_ushort4(h0, h1, h2, h3);
    if (lo) {
        float r0 = v.x - __uint_as_float((unsigned)h0 << 16);
        float r1 = v.y - __uint_as_float((unsigned)h1 << 16);
        float r2 = v.z - __uint_as_float((unsigned)h2 << 16);
        float r3 = v.w - __uint_as_float((unsigned)h3 << 16);
        ((ushort4*)lo)[j] = make_ushort4(f2bf_rne(r0), f2bf_rne(r1), f2bf_rne(r2), f2bf_rne(r3));
    }
}

// ---------------------------------------------------------------------------
// MFMA GEMM, m97 structure: 128x128 tile, BK=32, 4 waves x (4x4) 16x16x32 tiles.
// ---------------------------------------------------------------------------
template <int NTERMS, int EPI>
__global__ __launch_bounds__(256) void gemm_mfma(
    const ushort* __restrict__ Ah_g, const ushort* __restrict__ Al_g,
    const ushort* __restrict__ Wh_g, const ushort* __restrict__ Wl_g,
    const float* __restrict__ bias,
    float* __restrict__ out, int K, int Nout)
{
    __shared__ ushort smem[(NTERMS == 3 ? 4 : 2) * 4096];
    ushort* AhS = smem;
    ushort* AlS = (NTERMS == 3) ? smem + 4096 : nullptr;
    ushort* WhS = (NTERMS == 3) ? smem + 8192 : smem + 4096;
    ushort* WlS = (NTERMS == 3) ? smem + 12288 : nullptr;

    const int tid  = threadIdx.x;
    const int wid  = tid >> 6;
    const int lane = tid & 63;
    const int quad = lane >> 4;
    const int cl   = lane & 15;
    const int m0 = blockIdx.y * 128;
    const int n0 = blockIdx.x * 128;
    const int wm = (wid & 1) * 64;
    const int wn = (wid >> 1) * 64;

    const int srow = lane >> 2;
    const int scol = (lane & 3) * 8;

    const ushort* src; ushort* dst; int r0, c0, cn;
    if (NTERMS == 3) {
        src = (wid == 0) ? Ah_g : (wid == 1) ? Al_g : (wid == 2) ? Wh_g : Wl_g;
        dst = (wid == 0) ? AhS : (wid == 1) ? AlS : (wid == 2) ? WhS : WlS;
        r0 = (wid < 2) ? m0 : n0;
        c0 = 0; cn = 8;
    } else {
        src = (wid < 2) ? Ah_g : Wh_g;
        dst = (wid < 2) ? AhS : WhS;
        r0 = (wid < 2) ? m0 : n0;
        c0 = (wid & 1) * 4; cn = 4;
    }

    f32x4 acc[4][4];
#pragma unroll
    for (int i = 0; i < 4; ++i)
#pragma unroll
        for (int j = 0; j < 4; ++j) acc[i][j] = (f32x4){0.f, 0.f, 0.f, 0.f};

    for (int k0 = 0; k0 < K; k0 += 32) {
#pragma unroll
        for (int c = 0; c < ((NTERMS == 3) ? 8 : 4); ++c) {
            const int cc = c0 + (NTERMS == 3 ? c : (c & 3));
            if (NTERMS != 3 && c >= cn) break;
            const ushort* g = src + (size_t)(r0 + cc * 16 + srow) * K + k0 + scol;
            gl_lds16(g, dst + cc * 512);
        }
        __syncthreads();

        bf16x8 ah[4], wh[4];
#pragma unroll
        for (int i = 0; i < 4; ++i) {
            ah[i] = ((const bf16x8*)AhS)[(wm + i * 16 + cl) * 4 + quad];
            wh[i] = ((const bf16x8*)WhS)[(wn + i * 16 + cl) * 4 + quad];
        }
        if (NTERMS == 3) {
            bf16x8 al[4], wl[4];
#pragma unroll
            for (int i = 0; i < 4; ++i) {
                al[i] = ((const bf16x8*)AlS)[(wm + i * 16 + cl) * 4 + quad];
                wl[i] = ((const bf16x8*)WlS)[(wn + i * 16 + cl) * 4 + quad];
            }
#pragma unroll
            for (int mi = 0; mi < 4; ++mi)
#pragma unroll
                for (int ni = 0; ni < 4; ++ni) {
                    acc[mi][ni] = __builtin_amdgcn_mfma_f32_16x16x32_bf16(ah[mi], wh[ni], acc[mi][ni], 0, 0, 0);
                    acc[mi][ni] = __builtin_amdgcn_mfma_f32_16x16x32_bf16(ah[mi], wl[ni], acc[mi][ni], 0, 0, 0);
                    acc[mi][ni] = __builtin_amdgcn_mfma_f32_16x16x32_bf16(al[mi], wh[ni], acc[mi][ni], 0, 0, 0);
                }
        } else {
#pragma unroll
            for (int mi = 0; mi < 4; ++mi)
#pragma unroll
                for (int ni = 0; ni < 4; ++ni)
                    acc[mi][ni] = __builtin_amdgcn_mfma_f32_16x16x32_bf16(ah[mi], wh[ni], acc[mi][ni], 0, 0, 0);
        }
        __syncthreads();
    }

    if (EPI == 1) {
        float bb[4];
#pragma unroll
        for (int ni = 0; ni < 4; ++ni) bb[ni] = bias[n0 + wn + ni * 16 + cl];
#pragma unroll
        for (int mi = 0; mi < 4; ++mi)
#pragma unroll
            for (int r = 0; r < 4; ++r) {
                const int gm = m0 + wm + mi * 16 + quad * 4 + r;
                float* rowp = out + (size_t)gm * Nout;
#pragma unroll
                for (int ni = 0; ni < 4; ++ni) {
                    const int gn = n0 + wn + ni * 16 + cl;
                    rowp[gn] = acc[mi][ni][r] + bb[ni];
                }
            }
    } else {
#pragma unroll
        for (int mi = 0; mi < 4; ++mi)
#pragma unroll
            for (int r = 0; r < 4; ++r) {
                const int gm = m0 + wm + mi * 16 + quad * 4 + r;
                const int b  = gm >> 11;
                const int nn = gm & 2047;
#pragma unroll
                for (int ni = 0; ni < 4; ++ni) {
                    const int gn = n0 + wn + ni * 16 + cl;
                    const int s  = gn >> 10;
                    const int h  = (gn >> 6) & 15;
                    const int dh = gn & 63;
                    out[(size_t)s * 4194304u + (((size_t)b * 16 + h) * 2048 + nn) * 64 + dh]
                        = acc[mi][ni][r];
                }
            }
    }
}

// S_all[bh][d] = sum_n v[bh][n][d]
__global__ void sall_sum(const float* __restrict__ vg, float* __restrict__ sall)
{
    const int bx = blockIdx.x;
    const int bh = bx >> 3;
    const int chunk = bx & 7;
    const int d = threadIdx.x;
    const float* base = vg + (((size_t)bh * 2048) + (size_t)chunk * 256) * 64 + d;
    float s = 0.f;
#pragma unroll 8
    for (int nn = 0; nn < 256; ++nn) s += base[(size_t)nn * 64];
    atomicAdd(&sall[bh * 64 + d], s);
}

// ---------------------------------------------------------------------------
// Banded attention, LDS-free & barrier-free. 8 lanes own one query row
// (lane p = lane&7 owns dims [p*8, p*8+8)). All K/V reads straight from
// global (L1-resident band). Softmax computed redundantly on all 8 lanes.
// Block = 256 threads = 4 independent waves = 32 rows; grid = 2048.
// ---------------------------------------------------------------------------
__global__ __launch_bounds__(256) void attn_band(
    const float* __restrict__ qg,
    const float* __restrict__ kg,
    const float* __restrict__ vg,
    const float* __restrict__ sall,
    ushort* __restrict__ outp,
    const int* __restrict__ epoch_ptr)
{
    const int N = 2048;
    const int w = (epoch_ptr[0] < 15) ? 16 : 20;

    const int tid  = threadIdx.x;
    const int wid  = tid >> 6;
    const int lane = tid & 63;
    const int p    = lane & 7;          // dim-slice owner
    const int rg   = lane >> 3;         // 0..7 row within wave

    const int bh = blockIdx.x >> 6;                     // 0..31
    const int n  = ((blockIdx.x & 63) << 5) + wid * 8 + rg;

    const int jlo = max(0, n - w);
    const int jhi = min(N - 1, n + w);
    const int bc  = jhi - jlo + 1;      // <= 41

    // Q slice -> registers (8 lanes x 32B = contiguous 256B per row)
    const float* qp = qg + ((size_t)bh * N + n) * 64 + p * 8;
    const float4 q0 = ((const float4*)qp)[0];
    const float4 q1 = ((const float4*)qp)[1];

    // Phase B: logits straight from global K (L1 band ~10KB/wave)
    const float* kbase = kg + ((size_t)bh * N + jlo) * 64 + p * 8;
    float lg[44];
#pragma unroll
    for (int i = 0; i < 44; ++i) {
        if (i < bc) {
            const float4* kp = (const float4*)(kbase + (size_t)i * 64);
            float4 k0 = kp[0], k1 = kp[1];
            float t = q0.x*k0.x + q0.y*k0.y + q0.z*k0.z + q0.w*k0.w
                    + q1.x*k1.x + q1.y*k1.y + q1.z*k1.z + q1.w*k1.w;
            t += __shfl_xor(t, 1);
            t += __shfl_xor(t, 2);
            t += __shfl_xor(t, 4);
            lg[i] = 4.0f * t;
        }
    }

    // Phase C: exact full-row softmax (masked logits = 1e-9, count N-bc),
    // redundantly on all 8 lanes of the row group.
    float m = 1e-9f;
#pragma unroll
    for (int i = 0; i < 44; ++i)
        if (i < bc) m = fmaxf(m, lg[i]);
    const float em = __expf(1e-9f - m);
    float denom = (float)(N - bc) * em;
#pragma unroll
    for (int i = 0; i < 44; ++i)
        if (i < bc) { float e = __expf(lg[i] - m); lg[i] = e; denom += e; }
    const float inv = 1.0f / denom;
    const float pm = em * inv;
#pragma unroll
    for (int i = 0; i < 44; ++i)
        if (i < bc) lg[i] = (lg[i] - em) * inv;

    // Phase D: weighted V accumulation from global (same L1 band)
    float acc[8];
#pragma unroll
    for (int d = 0; d < 8; ++d) acc[d] = 0.f;
    const float* vbase = vg + ((size_t)bh * N + jlo) * 64 + p * 8;
#pragma unroll
    for (int i = 0; i < 44; ++i) {
        if (i < bc) {
            const float s = lg[i];
            const float4* v4 = (const float4*)(vbase + (size_t)i * 64);
            float4 va = v4[0], vb = v4[1];
            acc[0] += s * va.x; acc[1] += s * va.y; acc[2] += s * va.z; acc[3] += s * va.w;
            acc[4] += s * vb.x; acc[5] += s * vb.y; acc[6] += s * vb.z; acc[7] += s * vb.w;
        }
    }

    const int b = bh >> 4;
    const int h = bh & 15;
    const float* sp = sall + bh * 64 + p * 8;
    float4 s0 = ((const float4*)sp)[0], s1 = ((const float4*)sp)[1];
    float o[8];
    o[0] = acc[0] + pm * s0.x; o[1] = acc[1] + pm * s0.y;
    o[2] = acc[2] + pm * s0.z; o[3] = acc[3] + pm * s0.w;
    o[4] = acc[4] + pm * s1.x; o[5] = acc[5] + pm * s1.y;
    o[6] = acc[6] + pm * s1.z; o[7] = acc[7] + pm * s1.w;

    unsigned u[4];
#pragma unroll
    for (int j = 0; j < 4; ++j)
        u[j] = (unsigned)f2bf_rne(o[2 * j]) | ((unsigned)f2bf_rne(o[2 * j + 1]) << 16);
    uint4* dstv = (uint4*)(outp + (((size_t)b * N + n) * 1024) + h * 64 + p * 8);
    dstv[0] = make_uint4(u[0], u[1], u[2], u[3]);
}

extern "C" void kernel_launch(void* const* d_in, const int* in_sizes, int n_in,
                              void* d_out, int out_size, void* d_ws, size_t ws_size,
                              hipStream_t stream)
{
    const float* x      = (const float*)d_in[0];
    const float* qkv_w  = (const float*)d_in[1];
    const float* proj_w = (const float*)d_in[2];
    const float* proj_b = (const float*)d_in[3];
    const int*   epoch  = (const int*)d_in[4];
    float* out = (float*)d_out;

    const size_t BHND = (size_t)2 * 16 * 2048 * 64;   // 4,194,304
    const size_t XN = 4194304, WN = 3145728;

    float* qw   = (float*)d_ws;
    float* kw   = qw + BHND;
    float* vw   = kw + BHND;
    float* sall = vw + BHND;
    ushort* xh  = (ushort*)(sall + 4096);
    ushort* xl  = xh + XN;
    ushort* wh  = xl + XN;
    ushort* wl  = wh + WN;
    ushort* pwh = wl + WN;
    ushort* ao  = xh;   // alias: xh/xl dead after qkv gemm

    hipMemsetAsync(sall, 0, 2048 * sizeof(float), stream);

    split_all<<<dim3(8192), dim3(256), 0, stream>>>(
        x, qkv_w, proj_w, xh, xl, wh, wl, pwh);

    gemm_mfma<3, 0><<<dim3(24, 32), dim3(256), 0, stream>>>(
        xh, xl, wh, wl, nullptr, qw, 1024, 3072);

    sall_sum<<<dim3(256), dim3(64), 0, stream>>>(vw, sall);
    attn_band<<<dim3(2048), dim3(256), 0, stream>>>(qw, kw, vw, sall, ao, epoch);

    gemm_mfma<1, 1><<<dim3(8, 32), dim3(256), 0, stream>>>(
        ao, nullptr, pwh, nullptr, proj_b, out, 1024, 1024);
}